// Round 1
// baseline (599.261 us; speedup 1.0000x reference)
//
#include <hip/hip_runtime.h>
#include <math.h>

#define LQ   15000
#define LSZ  15000
#define NB   2
#define ROWS (NB*LQ)   // 30000
#define HGT  100
#define WID  150

// ---------------- fp32 tiled GEMM: C[M,N] = A[M,K] @ W[K,N] + bias, optional row mask ----------------
__global__ __launch_bounds__(256) void gemm_bias(
    const float* __restrict__ A, const float* __restrict__ W,
    const float* __restrict__ bias, float* __restrict__ C,
    int M, int N, int K, const unsigned char* __restrict__ row_mask)
{
    __shared__ float As[16][64];   // [k][m]
    __shared__ float Ws[16][64];   // [k][n]
    const int tid = threadIdx.x;
    const int m0 = blockIdx.x * 64;
    const int n0 = blockIdx.y * 64;
    const int tr = tid >> 4, tc = tid & 15;          // compute mapping: 16x16 threads, 4x4 each
    const int a_m = tid >> 2, a_k = (tid & 3) * 4;   // A-tile load mapping
    const int w_k = tid >> 4, w_n = (tid & 15) * 4;  // W-tile load mapping

    float acc[4][4];
    #pragma unroll
    for (int i = 0; i < 4; ++i)
        #pragma unroll
        for (int j = 0; j < 4; ++j) acc[i][j] = 0.f;

    for (int k0 = 0; k0 < K; k0 += 16) {
        float4 av = make_float4(0.f, 0.f, 0.f, 0.f);
        if (m0 + a_m < M)
            av = *reinterpret_cast<const float4*>(&A[(size_t)(m0 + a_m) * K + k0 + a_k]);
        As[a_k + 0][a_m] = av.x; As[a_k + 1][a_m] = av.y;
        As[a_k + 2][a_m] = av.z; As[a_k + 3][a_m] = av.w;

        float4 wv = make_float4(0.f, 0.f, 0.f, 0.f);
        if (n0 + w_n < N)
            wv = *reinterpret_cast<const float4*>(&W[(size_t)(k0 + w_k) * N + n0 + w_n]);
        *reinterpret_cast<float4*>(&Ws[w_k][w_n]) = wv;
        __syncthreads();

        #pragma unroll
        for (int k = 0; k < 16; ++k) {
            float4 a = *reinterpret_cast<const float4*>(&As[k][tr * 4]);
            float4 w = *reinterpret_cast<const float4*>(&Ws[k][tc * 4]);
            float af[4] = {a.x, a.y, a.z, a.w};
            float wf[4] = {w.x, w.y, w.z, w.w};
            #pragma unroll
            for (int i = 0; i < 4; ++i)
                #pragma unroll
                for (int j = 0; j < 4; ++j)
                    acc[i][j] = fmaf(af[i], wf[j], acc[i][j]);
        }
        __syncthreads();
    }

    if (n0 + tc * 4 < N) {
        int c = n0 + tc * 4;
        float bx = 0.f, by = 0.f, bz = 0.f, bw = 0.f;
        if (bias) { bx = bias[c]; by = bias[c + 1]; bz = bias[c + 2]; bw = bias[c + 3]; }
        #pragma unroll
        for (int i = 0; i < 4; ++i) {
            int r = m0 + tr * 4 + i;
            if (r < M) {
                float4 o;
                o.x = acc[i][0] + bx; o.y = acc[i][1] + by;
                o.z = acc[i][2] + bz; o.w = acc[i][3] + bw;
                if (row_mask && row_mask[r]) o = make_float4(0.f, 0.f, 0.f, 0.f);
                *reinterpret_cast<float4*>(&C[(size_t)r * N + c]) = o;
            }
        }
    }
}

// ---------------- LayerNorm over 256 cols: out = LN(in0 + f(in1)), f = gelu or id ----------------
__device__ inline float gelu_exact(float x) {
    return 0.5f * x * (1.f + erff(x * 0.70710678118654752440f));
}

__global__ __launch_bounds__(256) void ln_kernel(
    const float* __restrict__ in0, const float* __restrict__ in1,
    const float* __restrict__ g, const float* __restrict__ b,
    float* __restrict__ out, int rows, int apply_gelu)
{
    int row = blockIdx.x * 4 + (threadIdx.x >> 6);
    int lane = threadIdx.x & 63;
    if (row >= rows) return;
    size_t base = (size_t)row * 256 + lane * 4;
    float4 x = *reinterpret_cast<const float4*>(&in0[base]);
    if (in1) {
        float4 y = *reinterpret_cast<const float4*>(&in1[base]);
        if (apply_gelu) {
            y.x = gelu_exact(y.x); y.y = gelu_exact(y.y);
            y.z = gelu_exact(y.z); y.w = gelu_exact(y.w);
        }
        x.x += y.x; x.y += y.y; x.z += y.z; x.w += y.w;
    }
    float s  = x.x + x.y + x.z + x.w;
    float sq = x.x * x.x + x.y * x.y + x.z * x.z + x.w * x.w;
    #pragma unroll
    for (int o = 32; o > 0; o >>= 1) {
        s  += __shfl_xor(s,  o, 64);
        sq += __shfl_xor(sq, o, 64);
    }
    float mean = s * (1.f / 256.f);
    float var  = sq * (1.f / 256.f) - mean * mean;
    float rst  = rsqrtf(var + 1e-5f);
    int c = lane * 4;
    float4 o4;
    o4.x = (x.x - mean) * rst * g[c + 0] + b[c + 0];
    o4.y = (x.y - mean) * rst * g[c + 1] + b[c + 1];
    o4.z = (x.z - mean) * rst * g[c + 2] + b[c + 2];
    o4.w = (x.w - mean) * rst * g[c + 3] + b[c + 3];
    *reinterpret_cast<float4*>(&out[base]) = o4;
}

// ---------------- elementwise add (q = tgt + query_pos) ----------------
__global__ __launch_bounds__(256) void add_kernel(
    const float* __restrict__ a, const float* __restrict__ b,
    float* __restrict__ o, int n4)
{
    int i = blockIdx.x * 256 + threadIdx.x;
    if (i < n4) {
        float4 x = reinterpret_cast<const float4*>(a)[i];
        float4 y = reinterpret_cast<const float4*>(b)[i];
        x.x += y.x; x.y += y.y; x.z += y.z; x.w += y.w;
        reinterpret_cast<float4*>(o)[i] = x;
    }
}

// ---------------- softmax over 4 points per (row, head), in place ----------------
__global__ __launch_bounds__(256) void softmax4_kernel(float* __restrict__ aw, int ngroups)
{
    int i = blockIdx.x * 256 + threadIdx.x;
    if (i >= ngroups) return;
    size_t base = (size_t)i * 4;
    float v0 = aw[base], v1 = aw[base + 1], v2 = aw[base + 2], v3 = aw[base + 3];
    float m = fmaxf(fmaxf(v0, v1), fmaxf(v2, v3));
    float e0 = expf(v0 - m), e1 = expf(v1 - m), e2 = expf(v2 - m), e3 = expf(v3 - m);
    float r = 1.f / (e0 + e1 + e2 + e3);
    aw[base] = e0 * r; aw[base + 1] = e1 * r; aw[base + 2] = e2 * r; aw[base + 3] = e3 * r;
}

// ---------------- bc = b_out @ W_csa + b_csa ----------------
__global__ __launch_bounds__(256) void bias_combine_kernel(
    const float* __restrict__ b_out, const float* __restrict__ W_csa,
    const float* __restrict__ b_csa, float* __restrict__ bc)
{
    int j = threadIdx.x;
    float s = b_csa[j];
    for (int k = 0; k < 256; ++k) s = fmaf(b_out[k], W_csa[(size_t)k * 256 + j], s);
    bc[j] = s;
}

// ---------------- deformable bilinear sampling ----------------
__device__ inline float sample_one(const float* __restrict__ vb, int xi, int yi) {
    bool valid = (xi >= 0) & (xi < WID) & (yi >= 0) & (yi < HGT);
    int xc = min(max(xi, 0), WID - 1);
    int yc = min(max(yi, 0), HGT - 1);
    float v = vb[(size_t)(yc * WID + xc) * 256];
    return valid ? v : 0.f;
}

__global__ __launch_bounds__(256) void deform_sample_kernel(
    const float* __restrict__ value,   // [NB*LSZ, 256] = [n][s][h*32+d]
    const float* __restrict__ offs,    // [ROWS, 64]  (h*8 + p*2 + {x,y})
    const float* __restrict__ aw,      // [ROWS, 32]  (h*4 + p), softmaxed
    const float* __restrict__ refp,    // [ROWS, 2]   (L=1)
    float* __restrict__ out)           // [ROWS, 256]
{
    int grp = blockIdx.x * 8 + (threadIdx.x >> 5);  // (row, head) group, 32 lanes each
    int d = threadIdx.x & 31;
    int h = grp & 7;
    int r = grp >> 3;            // n*LQ + lq
    int n = r / LQ;
    float rx = refp[(size_t)r * 2 + 0];
    float ry = refp[(size_t)r * 2 + 1];
    const float* vb = value + ((size_t)n * LSZ) * 256 + h * 32 + d;
    float acc = 0.f;
    #pragma unroll
    for (int p = 0; p < 4; ++p) {
        float ox = offs[(size_t)r * 64 + h * 8 + p * 2 + 0];
        float oy = offs[(size_t)r * 64 + h * 8 + p * 2 + 1];
        float a  = aw[(size_t)r * 32 + h * 4 + p];
        // loc = ref + off/(W,H);  x = loc_x*W - 0.5, y = loc_y*H - 0.5 (grid_sample, align_corners=False)
        float x = (rx + ox * (1.f / (float)WID)) * (float)WID - 0.5f;
        float y = (ry + oy * (1.f / (float)HGT)) * (float)HGT - 0.5f;
        float x0f = floorf(x), y0f = floorf(y);
        float lx = x - x0f, ly = y - y0f;
        int x0 = (int)x0f, y0 = (int)y0f;
        float v00 = sample_one(vb, x0,     y0);
        float v10 = sample_one(vb, x0 + 1, y0);
        float v01 = sample_one(vb, x0,     y0 + 1);
        float v11 = sample_one(vb, x0 + 1, y0 + 1);
        float sv = v00 * (1.f - lx) * (1.f - ly) + v10 * lx * (1.f - ly)
                 + v01 * (1.f - lx) * ly        + v11 * lx * ly;
        acc = fmaf(a, sv, acc);
    }
    out[(size_t)r * 256 + h * 32 + d] = acc;
}

// ---------------- launcher ----------------
extern "C" void kernel_launch(void* const* d_in, const int* in_sizes, int n_in,
                              void* d_out, int out_size, void* d_ws, size_t ws_size,
                              hipStream_t stream)
{
    const float* tgt       = (const float*)d_in[0];
    const float* query_pos = (const float*)d_in[1];
    const float* refp      = (const float*)d_in[4];
    const float* src       = (const float*)d_in[6];
    const unsigned char* mask = (const unsigned char*)d_in[9];
    const float* W_dsa  = (const float*)d_in[10]; const float* b_dsa  = (const float*)d_in[11];
    const float* g_nds  = (const float*)d_in[12]; const float* b_nds  = (const float*)d_in[13];
    const float* W_off  = (const float*)d_in[14]; const float* b_off  = (const float*)d_in[15];
    const float* W_attn = (const float*)d_in[16]; const float* b_attn = (const float*)d_in[17];
    const float* W_val  = (const float*)d_in[18]; const float* b_val  = (const float*)d_in[19];
    const float* W_out  = (const float*)d_in[20]; const float* b_out  = (const float*)d_in[21];
    const float* W_csa  = (const float*)d_in[22]; const float* b_csa  = (const float*)d_in[23];
    const float* g_n1   = (const float*)d_in[24]; const float* b_n1   = (const float*)d_in[25];
    const float* W_ff   = (const float*)d_in[26]; const float* b_ff   = (const float*)d_in[27];
    const float* g_n3   = (const float*)d_in[28]; const float* b_n3   = (const float*)d_in[29];
    float* out = (float*)d_out;

    // workspace layout (fp32): two 30000x256 ping-pong buffers + small
    float* B0     = (float*)d_ws;                       // 30000*256
    float* B1     = B0 + (size_t)ROWS * 256;            // 30000*256
    float* S_off  = B1 + (size_t)ROWS * 256;            // 30000*64
    float* S_attn = S_off + (size_t)ROWS * 64;          // 30000*32
    float* Wc     = S_attn + (size_t)ROWS * 32;         // 256*256
    float* bc     = Wc + 256 * 256;                     // 256
    // total ~73.3 MB

    dim3 blk(256);
    dim3 gBig((ROWS + 63) / 64, 4);
    dim3 gNar((ROWS + 63) / 64, 1);

    // 1. B0 = src @ W_dsa + b_dsa ; then LN in place -> src_a
    gemm_bias<<<gBig, blk, 0, stream>>>(src, W_dsa, b_dsa, B0, ROWS, 256, 256, nullptr);
    ln_kernel<<<ROWS / 4, blk, 0, stream>>>(B0, nullptr, g_nds, b_nds, B0, ROWS, 0);
    // 2. B1 = value = src_a @ W_val + b_val (masked rows -> 0)
    gemm_bias<<<gBig, blk, 0, stream>>>(B0, W_val, b_val, B1, ROWS, 256, 256, mask);
    // 3. B0 = q = tgt + query_pos
    add_kernel<<<(ROWS * 256 / 4 + 255) / 256, blk, 0, stream>>>(tgt, query_pos, B0, ROWS * 256 / 4);
    // 4. sampling params
    gemm_bias<<<gNar, blk, 0, stream>>>(B0, W_off,  b_off,  S_off,  ROWS, 64, 256, nullptr);
    gemm_bias<<<gNar, blk, 0, stream>>>(B0, W_attn, b_attn, S_attn, ROWS, 32, 256, nullptr);
    softmax4_kernel<<<(ROWS * 8 + 255) / 256, blk, 0, stream>>>(S_attn, ROWS * 8);
    // 5. B0 = deformable attention output (q dead)
    deform_sample_kernel<<<ROWS, blk, 0, stream>>>(B1, S_off, S_attn, refp, B0);
    // 6. collapse W_out->W_csa chain: Wc = W_out @ W_csa ; bc = b_out @ W_csa + b_csa
    gemm_bias<<<dim3(4, 4), blk, 0, stream>>>(W_out, W_csa, nullptr, Wc, 256, 256, 256, nullptr);
    bias_combine_kernel<<<1, blk, 0, stream>>>(b_out, W_csa, b_csa, bc);
    // 7. B1 = tgt2 = attn_out @ Wc + bc (value dead)
    gemm_bias<<<gBig, blk, 0, stream>>>(B0, Wc, bc, B1, ROWS, 256, 256, nullptr);
    // 8. B0 = t = LN(tgt + tgt2)
    ln_kernel<<<ROWS / 4, blk, 0, stream>>>(tgt, B1, g_n1, b_n1, B0, ROWS, 0);
    // 9. B1 = t @ W_ff + b_ff
    gemm_bias<<<gBig, blk, 0, stream>>>(B0, W_ff, b_ff, B1, ROWS, 256, 256, nullptr);
    // 10. out = LN(t + gelu(B1))
    ln_kernel<<<ROWS / 4, blk, 0, stream>>>(B0, B1, g_n3, b_n3, out, ROWS, 1);
}

// Round 2
// 386.261 us; speedup vs baseline: 1.5514x; 1.5514x over previous
//
#include <hip/hip_runtime.h>
#include <hip/hip_bf16.h>
#include <math.h>

#define LQ   15000
#define LS_  15000
#define NB   2
#define ROWS (NB*LQ)   // 30000
#define HGT  100
#define WID  150
#define KDIM 256

typedef __attribute__((ext_vector_type(8))) short bf16x8;
typedef __attribute__((ext_vector_type(4))) float f32x4;

enum { EP_BIAS_F32 = 0, EP_LN_BF = 1, EP_MASK_BF = 2, EP_RES_LN_BF = 3, EP_GELU_RES_LN_F32 = 4 };

__device__ inline short f2bf(float x) {
    __hip_bfloat16 h = __float2bfloat16(x);
    return *reinterpret_cast<short*>(&h);
}
__device__ inline float bf2f(short s) {
    unsigned u = ((unsigned)(unsigned short)s) << 16;
    return __uint_as_float(u);
}
__device__ inline unsigned pack2bf(float a, float b) {
    return ((unsigned)(unsigned short)f2bf(a)) | (((unsigned)(unsigned short)f2bf(b)) << 16);
}
__device__ inline float gelu_exact(float x) {
    return 0.5f * x * (1.f + erff(x * 0.70710678118654752440f));
}

// ================= bf16 MFMA GEMM, BM=64, BN=NT*16, K=256, fused epilogues =================
// A: [M,256] fp32 (AF32) or bf16.  WT: [BN,256] bf16 = W^T.  Block owns full rows -> LN fusable.
template<int NT, int EPI, bool AF32>
__global__ __launch_bounds__(256) void mfma_gemm(
    const void* __restrict__ Ap, const short* __restrict__ WT,
    const float* __restrict__ bias, void* __restrict__ Out,
    const void* __restrict__ Res, const unsigned char* __restrict__ mask,
    const float* __restrict__ lng, const float* __restrict__ lnb, int M)
{
    constexpr int BN = NT * 16;
    __shared__ short As[64][40];     // [m][k], pad 40 -> 2-way-free LDS reads
    __shared__ short Bs[BN][40];     // [n][k]
    __shared__ float sbias[BN], sg[BN], sb2[BN];

    const int tid  = threadIdx.x;
    const int bm0  = blockIdx.x * 64;
    const int wave = tid >> 6, lane = tid & 63;
    const int quad = lane >> 4, c = lane & 15;

    if (tid < BN) {
        sbias[tid] = bias ? bias[tid] : 0.f;
        if (EPI == EP_LN_BF || EPI == EP_RES_LN_BF || EPI == EP_GELU_RES_LN_F32) {
            sg[tid] = lng[tid]; sb2[tid] = lnb[tid];
        }
    }

    f32x4 acc[NT];
    #pragma unroll
    for (int t = 0; t < NT; ++t) acc[t] = (f32x4){0.f, 0.f, 0.f, 0.f};

    for (int k0 = 0; k0 < KDIM; k0 += 32) {
        if (AF32) {
            const float* A = (const float*)Ap;
            #pragma unroll
            for (int it = 0; it < 2; ++it) {
                int f = it * 256 + tid; int m = f >> 3; int ko = (f & 7) * 4;
                int r = bm0 + m; if (r > M - 1) r = M - 1;
                float4 v = *(const float4*)&A[(size_t)r * KDIM + k0 + ko];
                int2 p; p.x = pack2bf(v.x, v.y); p.y = pack2bf(v.z, v.w);
                *(int2*)&As[m][ko] = p;
            }
        } else {
            const short* A = (const short*)Ap;
            int m = tid >> 2; int ko = (tid & 3) * 8;
            int r = bm0 + m; if (r > M - 1) r = M - 1;
            *(int4*)&As[m][ko] = *(const int4*)&A[(size_t)r * KDIM + k0 + ko];
        }
        #pragma unroll
        for (int it = 0; it < (BN * 4 + 255) / 256; ++it) {
            int f = it * 256 + tid;
            if (f < BN * 4) {
                int n = f >> 2; int ko = (f & 3) * 8;
                *(int4*)&Bs[n][ko] = *(const int4*)&WT[(size_t)n * KDIM + k0 + ko];
            }
        }
        __syncthreads();
        bf16x8 a = *(const bf16x8*)&As[wave * 16 + c][quad * 8];
        #pragma unroll
        for (int t = 0; t < NT; ++t) {
            bf16x8 b = *(const bf16x8*)&Bs[t * 16 + c][quad * 8];
            acc[t] = __builtin_amdgcn_mfma_f32_16x16x32_bf16(a, b, acc[t], 0, 0, 0);
        }
        __syncthreads();
    }

    // ---------------- epilogue: wave owns rows [bm0+wave*16, +16), cols t*16+c ----------------
    const int r0 = bm0 + wave * 16 + quad * 4;
    if constexpr (EPI == EP_BIAS_F32) {
        float* O = (float*)Out;
        #pragma unroll
        for (int reg = 0; reg < 4; ++reg) {
            int r = r0 + reg;
            if (r < M) {
                #pragma unroll
                for (int t = 0; t < NT; ++t)
                    O[(size_t)r * BN + t * 16 + c] = acc[t][reg] + sbias[t * 16 + c];
            }
        }
    } else if constexpr (EPI == EP_MASK_BF) {
        short* O = (short*)Out;
        #pragma unroll
        for (int reg = 0; reg < 4; ++reg) {
            int r = r0 + reg;
            if (r < M) {
                float mz = mask[r] ? 0.f : 1.f;
                #pragma unroll
                for (int t = 0; t < NT; ++t)
                    O[(size_t)r * 256 + t * 16 + c] = f2bf((acc[t][reg] + sbias[t * 16 + c]) * mz);
            }
        }
    } else {
        #pragma unroll
        for (int reg = 0; reg < 4; ++reg) {
            int r = r0 + reg;
            int rl = (r < M) ? r : (M - 1);
            float s = 0.f, sq = 0.f;
            #pragma unroll
            for (int t = 0; t < NT; ++t) {
                float v = acc[t][reg] + sbias[t * 16 + c];
                if constexpr (EPI == EP_GELU_RES_LN_F32) {
                    v = gelu_exact(v);
                    v += bf2f(((const short*)Res)[(size_t)rl * 256 + t * 16 + c]);
                } else if constexpr (EPI == EP_RES_LN_BF) {
                    v += ((const float*)Res)[(size_t)rl * 256 + t * 16 + c];
                }
                acc[t][reg] = v;
                s += v; sq += v * v;
            }
            #pragma unroll
            for (int o = 1; o < 16; o <<= 1) {
                s  += __shfl_xor(s,  o, 64);
                sq += __shfl_xor(sq, o, 64);
            }
            float mean = s * (1.f / 256.f);
            float var  = sq * (1.f / 256.f) - mean * mean;
            float rs   = rsqrtf(var + 1e-5f);
            if (r < M) {
                #pragma unroll
                for (int t = 0; t < NT; ++t) {
                    float o = (acc[t][reg] - mean) * rs * sg[t * 16 + c] + sb2[t * 16 + c];
                    if constexpr (EPI == EP_GELU_RES_LN_F32)
                        ((float*)Out)[(size_t)r * 256 + t * 16 + c] = o;
                    else
                        ((short*)Out)[(size_t)r * 256 + t * 16 + c] = f2bf(o);
                }
            }
        }
    }
}

// ================= q = tgt + query_pos -> bf16 =================
__global__ __launch_bounds__(256) void add_q_bf(
    const float* __restrict__ a, const float* __restrict__ b, short* __restrict__ o, int n4)
{
    int i = blockIdx.x * 256 + threadIdx.x;
    if (i < n4) {
        float4 x = reinterpret_cast<const float4*>(a)[i];
        float4 y = reinterpret_cast<const float4*>(b)[i];
        int2 p; p.x = pack2bf(x.x + y.x, x.y + y.y); p.y = pack2bf(x.z + y.z, x.w + y.w);
        reinterpret_cast<int2*>(o)[i] = p;
    }
}

// ================= weight prep =================
__global__ __launch_bounds__(256) void transp_cvt(const float* __restrict__ W, short* __restrict__ WT)
{
    __shared__ float tile[64][65];
    int bx = blockIdx.x * 64, by = blockIdx.y * 64;
    int tid = threadIdx.x;
    #pragma unroll
    for (int it = 0; it < 4; ++it) {
        int f = it * 256 + tid; int i = f >> 4; int j = (f & 15) * 4;
        float4 v = *(const float4*)&W[(size_t)(by + i) * 256 + bx + j];
        tile[i][j] = v.x; tile[i][j + 1] = v.y; tile[i][j + 2] = v.z; tile[i][j + 3] = v.w;
    }
    __syncthreads();
    #pragma unroll
    for (int it = 0; it < 16; ++it) {
        int f = it * 256 + tid; int nl = f >> 6; int kl = f & 63;
        WT[(size_t)(bx + nl) * 256 + by + kl] = f2bf(tile[kl][nl]);
    }
}

__global__ __launch_bounds__(256) void wc_kernel(
    const float* __restrict__ W_out, const float* __restrict__ W_csa, short* __restrict__ WT_c)
{
    int n = blockIdx.x, k = threadIdx.x;
    float s = 0.f;
    for (int j = 0; j < 256; ++j)
        s = fmaf(W_out[(size_t)k * 256 + j], W_csa[(size_t)j * 256 + n], s);
    WT_c[(size_t)n * 256 + k] = f2bf(s);
}

__global__ __launch_bounds__(256) void bias_combine_kernel(
    const float* __restrict__ b_out, const float* __restrict__ W_csa,
    const float* __restrict__ b_csa, float* __restrict__ bc)
{
    int j = threadIdx.x;
    float s = b_csa[j];
    for (int k = 0; k < 256; ++k) s = fmaf(b_out[k], W_csa[(size_t)k * 256 + j], s);
    bc[j] = s;
}

__global__ __launch_bounds__(256) void pack_oa(
    const float* __restrict__ W_off, const float* __restrict__ W_attn,
    const float* __restrict__ b_off, const float* __restrict__ b_attn,
    short* __restrict__ WT_oa, float* __restrict__ b_oa)
{
    int j = blockIdx.x, k = threadIdx.x;
    float v = (j < 64) ? W_off[(size_t)k * 64 + j] : W_attn[(size_t)k * 32 + (j - 64)];
    WT_oa[(size_t)j * 256 + k] = f2bf(v);
    if (k == 0) b_oa[j] = (j < 64) ? b_off[j] : b_attn[j - 64];
}

// ================= deformable sampling, softmax fused, bf16 value =================
__device__ inline float sample_bf(const short* __restrict__ vb, int xi, int yi) {
    bool valid = (xi >= 0) & (xi < WID) & (yi >= 0) & (yi < HGT);
    int xc = min(max(xi, 0), WID - 1);
    int yc = min(max(yi, 0), HGT - 1);
    float v = bf2f(vb[(size_t)(yc * WID + xc) * 256]);
    return valid ? v : 0.f;
}

__global__ __launch_bounds__(256) void deform_sample(
    const short* __restrict__ value,   // [NB*LS_, 256] bf16
    const float* __restrict__ S_oa,    // [ROWS, 96]: 0..63 offsets, 64..95 attn logits
    const float* __restrict__ refp,    // [ROWS, 2]
    short* __restrict__ out)           // [ROWS, 256] bf16
{
    int grp = blockIdx.x * 8 + (threadIdx.x >> 5);
    int d = threadIdx.x & 31;
    int h = grp & 7;
    int r = grp >> 3;
    int n = r / LQ;
    const float* row = S_oa + (size_t)r * 96;
    float rx = refp[(size_t)r * 2 + 0], ry = refp[(size_t)r * 2 + 1];
    // softmax over 4 logits (redundant per lane, broadcast reads)
    float l0 = row[64 + h * 4 + 0], l1 = row[64 + h * 4 + 1];
    float l2 = row[64 + h * 4 + 2], l3 = row[64 + h * 4 + 3];
    float mx = fmaxf(fmaxf(l0, l1), fmaxf(l2, l3));
    float e0 = expf(l0 - mx), e1 = expf(l1 - mx), e2 = expf(l2 - mx), e3 = expf(l3 - mx);
    float inv = 1.f / (e0 + e1 + e2 + e3);
    float aw[4] = {e0 * inv, e1 * inv, e2 * inv, e3 * inv};

    const short* vb = value + ((size_t)n * LS_) * 256 + h * 32 + d;
    float acc = 0.f;
    #pragma unroll
    for (int p = 0; p < 4; ++p) {
        float ox = row[h * 8 + p * 2 + 0];
        float oy = row[h * 8 + p * 2 + 1];
        float x = rx * (float)WID + ox - 0.5f;   // (rx + ox/W)*W - 0.5
        float y = ry * (float)HGT + oy - 0.5f;
        float x0f = floorf(x), y0f = floorf(y);
        float lx = x - x0f, ly = y - y0f;
        int x0 = (int)x0f, y0 = (int)y0f;
        float v00 = sample_bf(vb, x0,     y0);
        float v10 = sample_bf(vb, x0 + 1, y0);
        float v01 = sample_bf(vb, x0,     y0 + 1);
        float v11 = sample_bf(vb, x0 + 1, y0 + 1);
        float sv = v00 * (1.f - lx) * (1.f - ly) + v10 * lx * (1.f - ly)
                 + v01 * (1.f - lx) * ly        + v11 * lx * ly;
        acc = fmaf(aw[p], sv, acc);
    }
    out[(size_t)r * 256 + h * 32 + d] = f2bf(acc);
}

// ================= launcher =================
extern "C" void kernel_launch(void* const* d_in, const int* in_sizes, int n_in,
                              void* d_out, int out_size, void* d_ws, size_t ws_size,
                              hipStream_t stream)
{
    const float* tgt       = (const float*)d_in[0];
    const float* query_pos = (const float*)d_in[1];
    const float* refp      = (const float*)d_in[4];
    const float* src       = (const float*)d_in[6];
    const unsigned char* mask = (const unsigned char*)d_in[9];
    const float* W_dsa  = (const float*)d_in[10]; const float* b_dsa  = (const float*)d_in[11];
    const float* g_nds  = (const float*)d_in[12]; const float* b_nds  = (const float*)d_in[13];
    const float* W_off  = (const float*)d_in[14]; const float* b_off  = (const float*)d_in[15];
    const float* W_attn = (const float*)d_in[16]; const float* b_attn = (const float*)d_in[17];
    const float* W_val  = (const float*)d_in[18]; const float* b_val  = (const float*)d_in[19];
    const float* W_out  = (const float*)d_in[20]; const float* b_out  = (const float*)d_in[21];
    const float* W_csa  = (const float*)d_in[22]; const float* b_csa  = (const float*)d_in[23];
    const float* g_n1   = (const float*)d_in[24]; const float* b_n1   = (const float*)d_in[25];
    const float* W_ff   = (const float*)d_in[26]; const float* b_ff   = (const float*)d_in[27];
    const float* g_n3   = (const float*)d_in[28]; const float* b_n3   = (const float*)d_in[29];
    float* out = (float*)d_out;

    // workspace layout
    short* bf0   = (short*)d_ws;                         // src_a, then attn_out  [30000*256 bf16]
    short* bf1   = bf0 + (size_t)ROWS * 256;             // q, then t             [30000*256 bf16]
    short* bf2   = bf1 + (size_t)ROWS * 256;             // value                 [30000*256 bf16]
    float* S_oa  = (float*)(bf2 + (size_t)ROWS * 256);   // [30000*96] f32
    short* WT_dsa = (short*)(S_oa + (size_t)ROWS * 96);
    short* WT_val = WT_dsa + 65536;
    short* WT_c   = WT_val + 65536;
    short* WT_ff  = WT_c + 65536;
    short* WT_oa  = WT_ff + 65536;                       // 96*256
    float* bc     = (float*)(WT_oa + 96 * 256);
    float* b_oa   = bc + 256;
    // total ~58.3 MB

    dim3 blk(256);
    const int GB = (ROWS + 63) / 64;   // 469

    // weight prep (independent, tiny)
    transp_cvt<<<dim3(4, 4), blk, 0, stream>>>(W_dsa, WT_dsa);
    transp_cvt<<<dim3(4, 4), blk, 0, stream>>>(W_val, WT_val);
    transp_cvt<<<dim3(4, 4), blk, 0, stream>>>(W_ff,  WT_ff);
    wc_kernel<<<256, blk, 0, stream>>>(W_out, W_csa, WT_c);
    bias_combine_kernel<<<1, blk, 0, stream>>>(b_out, W_csa, b_csa, bc);
    pack_oa<<<96, blk, 0, stream>>>(W_off, W_attn, b_off, b_attn, WT_oa, b_oa);
    add_q_bf<<<(ROWS * 64 + 255) / 256, blk, 0, stream>>>(tgt, query_pos, bf1, ROWS * 64);

    // 1. src_a = LN(src @ W_dsa + b_dsa)   [fp32 A, bf16 out]
    mfma_gemm<16, EP_LN_BF, true><<<GB, blk, 0, stream>>>(
        src, WT_dsa, b_dsa, bf0, nullptr, nullptr, g_nds, b_nds, ROWS);
    // 2. value = mask(src_a @ W_val + b_val)
    mfma_gemm<16, EP_MASK_BF, false><<<GB, blk, 0, stream>>>(
        bf0, WT_val, b_val, bf2, nullptr, mask, nullptr, nullptr, ROWS);
    // 3. S_oa = q @ [W_off|W_attn] + [b_off|b_attn]
    mfma_gemm<6, EP_BIAS_F32, false><<<GB, blk, 0, stream>>>(
        bf1, WT_oa, b_oa, S_oa, nullptr, nullptr, nullptr, nullptr, ROWS);
    // 4. attn_out = deform-sample (softmax fused)
    deform_sample<<<ROWS, blk, 0, stream>>>(bf2, S_oa, refp, bf0);
    // 5. t = LN(tgt + attn_out @ Wc + bc)   [Wc = W_out @ W_csa]
    mfma_gemm<16, EP_RES_LN_BF, false><<<GB, blk, 0, stream>>>(
        bf0, WT_c, bc, bf1, tgt, nullptr, g_n1, b_n1, ROWS);
    // 6. out = LN(t + gelu(t @ W_ff + b_ff))
    mfma_gemm<16, EP_GELU_RES_LN_F32, false><<<GB, blk, 0, stream>>>(
        bf1, WT_ff, b_ff, out, bf1, nullptr, g_n3, b_n3, ROWS);
}

// Round 3
// 346.964 us; speedup vs baseline: 1.7272x; 1.1133x over previous
//
#include <hip/hip_runtime.h>
#include <hip/hip_bf16.h>
#include <math.h>

#define LQ   15000
#define LS_  15000
#define NB   2
#define ROWS (NB*LQ)   // 30000
#define HGT  100
#define WID  150
#define KDIM 256

typedef __attribute__((ext_vector_type(8))) short bf16x8;
typedef __attribute__((ext_vector_type(4))) float f32x4;

enum { EP_BIAS_F32 = 0, EP_LN_BF = 1, EP_MASK_HM = 2, EP_RES_LN_BF = 3, EP_GELU_RES_LN_F32 = 4 };
enum { AM_BF16 = 0, AM_F32 = 1, AM_F32SUM = 2 };

__device__ inline short f2bf(float x) {
    __hip_bfloat16 h = __float2bfloat16(x);
    return *reinterpret_cast<short*>(&h);
}
__device__ inline unsigned pack2bf(float a, float b) {
    return ((unsigned)(unsigned short)f2bf(a)) | (((unsigned)(unsigned short)f2bf(b)) << 16);
}
__device__ inline float bf2f(short s) {
    return __uint_as_float(((unsigned)(unsigned short)s) << 16);
}
__device__ inline float gelu_exact(float x) {
    return 0.5f * x * (1.f + erff(x * 0.70710678118654752440f));
}

// ================= bf16 MFMA GEMM, BM=64, BN=NT*16, K=256, fused epilogues =================
template<int NT, int EPI, int AMODE>
__global__ __launch_bounds__(256) void mfma_gemm(
    const void* __restrict__ Ap, const void* __restrict__ Ap2,
    const short* __restrict__ WT,
    const float* __restrict__ bias, void* __restrict__ Out,
    const void* __restrict__ Res, const unsigned char* __restrict__ mask,
    const float* __restrict__ lng, const float* __restrict__ lnb, int M)
{
    constexpr int BN = NT * 16;
    __shared__ short As[64][40];
    __shared__ short Bs[BN][40];
    __shared__ float sbias[BN], sg[BN], sb2[BN];

    const int tid  = threadIdx.x;
    const int bm0  = blockIdx.x * 64;
    const int wave = tid >> 6, lane = tid & 63;
    const int quad = lane >> 4, c = lane & 15;

    if (tid < BN) {
        sbias[tid] = bias ? bias[tid] : 0.f;
        if (EPI == EP_LN_BF || EPI == EP_RES_LN_BF || EPI == EP_GELU_RES_LN_F32) {
            sg[tid] = lng[tid]; sb2[tid] = lnb[tid];
        }
    }

    f32x4 acc[NT];
    #pragma unroll
    for (int t = 0; t < NT; ++t) acc[t] = (f32x4){0.f, 0.f, 0.f, 0.f};

    for (int k0 = 0; k0 < KDIM; k0 += 32) {
        if (AMODE != AM_BF16) {
            const float* A  = (const float*)Ap;
            const float* A2 = (const float*)Ap2;
            #pragma unroll
            for (int it = 0; it < 2; ++it) {
                int f = it * 256 + tid; int m = f >> 3; int ko = (f & 7) * 4;
                int r = bm0 + m; if (r > M - 1) r = M - 1;
                float4 v = *(const float4*)&A[(size_t)r * KDIM + k0 + ko];
                if (AMODE == AM_F32SUM) {
                    float4 w = *(const float4*)&A2[(size_t)r * KDIM + k0 + ko];
                    v.x += w.x; v.y += w.y; v.z += w.z; v.w += w.w;
                }
                int2 p; p.x = pack2bf(v.x, v.y); p.y = pack2bf(v.z, v.w);
                *(int2*)&As[m][ko] = p;
            }
        } else {
            const short* A = (const short*)Ap;
            int m = tid >> 2; int ko = (tid & 3) * 8;
            int r = bm0 + m; if (r > M - 1) r = M - 1;
            *(int4*)&As[m][ko] = *(const int4*)&A[(size_t)r * KDIM + k0 + ko];
        }
        #pragma unroll
        for (int it = 0; it < (BN * 4 + 255) / 256; ++it) {
            int f = it * 256 + tid;
            if (f < BN * 4) {
                int n = f >> 2; int ko = (f & 3) * 8;
                *(int4*)&Bs[n][ko] = *(const int4*)&WT[(size_t)n * KDIM + k0 + ko];
            }
        }
        __syncthreads();
        bf16x8 a = *(const bf16x8*)&As[wave * 16 + c][quad * 8];
        #pragma unroll
        for (int t = 0; t < NT; ++t) {
            bf16x8 b = *(const bf16x8*)&Bs[t * 16 + c][quad * 8];
            acc[t] = __builtin_amdgcn_mfma_f32_16x16x32_bf16(a, b, acc[t], 0, 0, 0);
        }
        __syncthreads();
    }

    const int r0 = bm0 + wave * 16 + quad * 4;
    if constexpr (EPI == EP_BIAS_F32) {
        float* O = (float*)Out;
        #pragma unroll
        for (int reg = 0; reg < 4; ++reg) {
            int r = r0 + reg;
            if (r < M) {
                #pragma unroll
                for (int t = 0; t < NT; ++t)
                    O[(size_t)r * BN + t * 16 + c] = acc[t][reg] + sbias[t * 16 + c];
            }
        }
    } else if constexpr (EPI == EP_MASK_HM) {
        // head-major value: O[((n*8+h)*LS_+s)*32 + d], n=r/LS_, s=r%LS_, h=col>>5, d=col&31
        short* O = (short*)Out;
        #pragma unroll
        for (int reg = 0; reg < 4; ++reg) {
            int r = r0 + reg;
            if (r < M) {
                float mz = mask[r] ? 0.f : 1.f;
                int n = (r >= LS_) ? 1 : 0;
                int s = r - n * LS_;
                #pragma unroll
                for (int t = 0; t < NT; ++t) {
                    int col = t * 16 + c;
                    int h = col >> 5, d = col & 31;
                    O[(((size_t)n * 8 + h) * LS_ + s) * 32 + d] =
                        f2bf((acc[t][reg] + sbias[col]) * mz);
                }
            }
        }
    } else {
        #pragma unroll
        for (int reg = 0; reg < 4; ++reg) {
            int r = r0 + reg;
            int rl = (r < M) ? r : (M - 1);
            float s = 0.f, sq = 0.f;
            #pragma unroll
            for (int t = 0; t < NT; ++t) {
                float v = acc[t][reg] + sbias[t * 16 + c];
                if constexpr (EPI == EP_GELU_RES_LN_F32) {
                    v = gelu_exact(v);
                    v += bf2f(((const short*)Res)[(size_t)rl * 256 + t * 16 + c]);
                } else if constexpr (EPI == EP_RES_LN_BF) {
                    v += ((const float*)Res)[(size_t)rl * 256 + t * 16 + c];
                }
                acc[t][reg] = v;
                s += v; sq += v * v;
            }
            #pragma unroll
            for (int o = 1; o < 16; o <<= 1) {
                s  += __shfl_xor(s,  o, 64);
                sq += __shfl_xor(sq, o, 64);
            }
            float mean = s * (1.f / 256.f);
            float var  = sq * (1.f / 256.f) - mean * mean;
            float rs   = rsqrtf(var + 1e-5f);
            if (r < M) {
                #pragma unroll
                for (int t = 0; t < NT; ++t) {
                    float o = (acc[t][reg] - mean) * rs * sg[t * 16 + c] + sb2[t * 16 + c];
                    if constexpr (EPI == EP_GELU_RES_LN_F32)
                        ((float*)Out)[(size_t)r * 256 + t * 16 + c] = o;
                    else
                        ((short*)Out)[(size_t)r * 256 + t * 16 + c] = f2bf(o);
                }
            }
        }
    }
}

// ================= weight prep =================
__global__ __launch_bounds__(256) void transp_cvt(const float* __restrict__ W, short* __restrict__ WT)
{
    __shared__ float tile[64][65];
    int bx = blockIdx.x * 64, by = blockIdx.y * 64;
    int tid = threadIdx.x;
    #pragma unroll
    for (int it = 0; it < 4; ++it) {
        int f = it * 256 + tid; int i = f >> 4; int j = (f & 15) * 4;
        float4 v = *(const float4*)&W[(size_t)(by + i) * 256 + bx + j];
        tile[i][j] = v.x; tile[i][j + 1] = v.y; tile[i][j + 2] = v.z; tile[i][j + 3] = v.w;
    }
    __syncthreads();
    #pragma unroll
    for (int it = 0; it < 16; ++it) {
        int f = it * 256 + tid; int nl = f >> 6; int kl = f & 63;
        WT[(size_t)(bx + nl) * 256 + by + kl] = f2bf(tile[kl][nl]);
    }
}

// Wc^T[n][k] = sum_j W_out[k][j] * W_csa[j][n]; k=block (SGPR loads), n=thread (coalesced)
__global__ __launch_bounds__(256) void wc_kernel(
    const float* __restrict__ W_out, const float* __restrict__ W_csa, short* __restrict__ WT_c)
{
    int k = blockIdx.x, n = threadIdx.x;
    float s = 0.f;
    for (int j = 0; j < 256; ++j)
        s = fmaf(W_out[(size_t)k * 256 + j], W_csa[(size_t)j * 256 + n], s);
    WT_c[(size_t)n * 256 + k] = f2bf(s);
}

__global__ __launch_bounds__(256) void bias_combine_kernel(
    const float* __restrict__ b_out, const float* __restrict__ W_csa,
    const float* __restrict__ b_csa, float* __restrict__ bc)
{
    int j = threadIdx.x;
    float s = b_csa[j];
    for (int k = 0; k < 256; ++k) s = fmaf(b_out[k], W_csa[(size_t)k * 256 + j], s);
    bc[j] = s;
}

__global__ __launch_bounds__(256) void pack_oa(
    const float* __restrict__ W_off, const float* __restrict__ W_attn,
    const float* __restrict__ b_off, const float* __restrict__ b_attn,
    short* __restrict__ WT_oa, float* __restrict__ b_oa)
{
    int j = blockIdx.x, k = threadIdx.x;
    float v = (j < 64) ? W_off[(size_t)k * 64 + j] : W_attn[(size_t)k * 32 + (j - 64)];
    WT_oa[(size_t)j * 256 + k] = f2bf(v);
    if (k == 0) b_oa[j] = (j < 64) ? b_off[j] : b_attn[j - 64];
}

// ================= deformable sampling: 8 lanes per (r,h), 4 channels/lane =================
__global__ __launch_bounds__(256) void deform_sample(
    const short* __restrict__ value,   // [NB][8][LS_][32] bf16, head-major
    const float* __restrict__ S_oa,    // [ROWS, 96]: 0..63 offsets, 64..95 attn logits
    const float* __restrict__ refp,    // [ROWS, 2]
    short* __restrict__ out)           // [ROWS, 256] bf16, h*32+d layout
{
    int grp = blockIdx.x * 32 + (threadIdx.x >> 3);
    int c4  = threadIdx.x & 7;
    int h = grp & 7;
    int r = grp >> 3;
    int n = (r >= LS_) ? 1 : 0;

    const float* row = S_oa + (size_t)r * 96;
    float rx = refp[(size_t)r * 2 + 0], ry = refp[(size_t)r * 2 + 1];
    float4 oA = *(const float4*)&row[h * 8];
    float4 oB = *(const float4*)&row[h * 8 + 4];
    float4 lg = *(const float4*)&row[64 + h * 4];

    float mx = fmaxf(fmaxf(lg.x, lg.y), fmaxf(lg.z, lg.w));
    float e0 = expf(lg.x - mx), e1 = expf(lg.y - mx), e2 = expf(lg.z - mx), e3 = expf(lg.w - mx);
    float inv = 1.f / (e0 + e1 + e2 + e3);
    float aw[4] = {e0 * inv, e1 * inv, e2 * inv, e3 * inv};
    float ox[4] = {oA.x, oA.z, oB.x, oB.z};
    float oy[4] = {oA.y, oA.w, oB.y, oB.w};

    const short* vb = value + (((size_t)n * 8 + h) * LS_) * 32 + c4 * 4;
    float a0 = 0.f, a1 = 0.f, a2 = 0.f, a3 = 0.f;

    #pragma unroll
    for (int p = 0; p < 4; ++p) {
        float x = rx * (float)WID + ox[p] - 0.5f;
        float y = ry * (float)HGT + oy[p] - 0.5f;
        float x0f = floorf(x), y0f = floorf(y);
        float lx = x - x0f, ly = y - y0f;
        int x0 = (int)x0f, y0 = (int)y0f;
        int x1 = x0 + 1, y1 = y0 + 1;
        bool vx0 = (x0 >= 0) & (x0 < WID), vx1 = (x1 >= 0) & (x1 < WID);
        bool vy0 = (y0 >= 0) & (y0 < HGT), vy1 = (y1 >= 0) & (y1 < HGT);
        float w00 = (vx0 & vy0) ? (1.f - lx) * (1.f - ly) * aw[p] : 0.f;
        float w10 = (vx1 & vy0) ? lx * (1.f - ly) * aw[p] : 0.f;
        float w01 = (vx0 & vy1) ? (1.f - lx) * ly * aw[p] : 0.f;
        float w11 = (vx1 & vy1) ? lx * ly * aw[p] : 0.f;
        int xc0 = min(max(x0, 0), WID - 1), xc1 = min(max(x1, 0), WID - 1);
        int yc0 = min(max(y0, 0), HGT - 1), yc1 = min(max(y1, 0), HGT - 1);
        int2 v00 = *(const int2*)&vb[(size_t)(yc0 * WID + xc0) * 32];
        int2 v10 = *(const int2*)&vb[(size_t)(yc0 * WID + xc1) * 32];
        int2 v01 = *(const int2*)&vb[(size_t)(yc1 * WID + xc0) * 32];
        int2 v11 = *(const int2*)&vb[(size_t)(yc1 * WID + xc1) * 32];
        // unpack bf16 pairs: low = <<16, high = mask
        a0 += w00 * __uint_as_float(((unsigned)v00.x) << 16)
            + w10 * __uint_as_float(((unsigned)v10.x) << 16)
            + w01 * __uint_as_float(((unsigned)v01.x) << 16)
            + w11 * __uint_as_float(((unsigned)v11.x) << 16);
        a1 += w00 * __uint_as_float(v00.x & 0xffff0000u)
            + w10 * __uint_as_float(v10.x & 0xffff0000u)
            + w01 * __uint_as_float(v01.x & 0xffff0000u)
            + w11 * __uint_as_float(v11.x & 0xffff0000u);
        a2 += w00 * __uint_as_float(((unsigned)v00.y) << 16)
            + w10 * __uint_as_float(((unsigned)v10.y) << 16)
            + w01 * __uint_as_float(((unsigned)v01.y) << 16)
            + w11 * __uint_as_float(((unsigned)v11.y) << 16);
        a3 += w00 * __uint_as_float(v00.y & 0xffff0000u)
            + w10 * __uint_as_float(v10.y & 0xffff0000u)
            + w01 * __uint_as_float(v01.y & 0xffff0000u)
            + w11 * __uint_as_float(v11.y & 0xffff0000u);
    }
    int2 o;
    o.x = pack2bf(a0, a1);
    o.y = pack2bf(a2, a3);
    *(int2*)&out[(size_t)r * 256 + h * 32 + c4 * 4] = o;
}

// ================= launcher =================
extern "C" void kernel_launch(void* const* d_in, const int* in_sizes, int n_in,
                              void* d_out, int out_size, void* d_ws, size_t ws_size,
                              hipStream_t stream)
{
    const float* tgt       = (const float*)d_in[0];
    const float* query_pos = (const float*)d_in[1];
    const float* refp      = (const float*)d_in[4];
    const float* src       = (const float*)d_in[6];
    const unsigned char* mask = (const unsigned char*)d_in[9];
    const float* W_dsa  = (const float*)d_in[10]; const float* b_dsa  = (const float*)d_in[11];
    const float* g_nds  = (const float*)d_in[12]; const float* b_nds  = (const float*)d_in[13];
    const float* W_off  = (const float*)d_in[14]; const float* b_off  = (const float*)d_in[15];
    const float* W_attn = (const float*)d_in[16]; const float* b_attn = (const float*)d_in[17];
    const float* W_val  = (const float*)d_in[18]; const float* b_val  = (const float*)d_in[19];
    const float* W_out  = (const float*)d_in[20]; const float* b_out  = (const float*)d_in[21];
    const float* W_csa  = (const float*)d_in[22]; const float* b_csa  = (const float*)d_in[23];
    const float* g_n1   = (const float*)d_in[24]; const float* b_n1   = (const float*)d_in[25];
    const float* W_ff   = (const float*)d_in[26]; const float* b_ff   = (const float*)d_in[27];
    const float* g_n3   = (const float*)d_in[28]; const float* b_n3   = (const float*)d_in[29];
    float* out = (float*)d_out;

    short* bf0   = (short*)d_ws;                         // src_a, then attn_out
    short* bf1   = bf0 + (size_t)ROWS * 256;             // t
    short* bf2   = bf1 + (size_t)ROWS * 256;             // value (head-major)
    float* S_oa  = (float*)(bf2 + (size_t)ROWS * 256);   // [30000*96] f32
    short* WT_dsa = (short*)(S_oa + (size_t)ROWS * 96);
    short* WT_val = WT_dsa + 65536;
    short* WT_c   = WT_val + 65536;
    short* WT_ff  = WT_c + 65536;
    short* WT_oa  = WT_ff + 65536;                       // 96*256
    float* bc     = (float*)(WT_oa + 96 * 256);
    float* b_oa   = bc + 256;

    dim3 blk(256);
    const int GB = (ROWS + 63) / 64;   // 469

    transp_cvt<<<dim3(4, 4), blk, 0, stream>>>(W_dsa, WT_dsa);
    transp_cvt<<<dim3(4, 4), blk, 0, stream>>>(W_val, WT_val);
    transp_cvt<<<dim3(4, 4), blk, 0, stream>>>(W_ff,  WT_ff);
    wc_kernel<<<256, blk, 0, stream>>>(W_out, W_csa, WT_c);
    bias_combine_kernel<<<1, blk, 0, stream>>>(b_out, W_csa, b_csa, bc);
    pack_oa<<<96, blk, 0, stream>>>(W_off, W_attn, b_off, b_attn, WT_oa, b_oa);

    // 1. src_a = LN(src @ W_dsa + b_dsa)
    mfma_gemm<16, EP_LN_BF, AM_F32><<<GB, blk, 0, stream>>>(
        src, nullptr, WT_dsa, b_dsa, bf0, nullptr, nullptr, g_nds, b_nds, ROWS);
    // 2. value = mask(src_a @ W_val + b_val), head-major layout
    mfma_gemm<16, EP_MASK_HM, AM_BF16><<<GB, blk, 0, stream>>>(
        bf0, nullptr, WT_val, b_val, bf2, nullptr, mask, nullptr, nullptr, ROWS);
    // 3. S_oa = (tgt+query_pos) @ [W_off|W_attn] + b   (q fused into staging)
    mfma_gemm<6, EP_BIAS_F32, AM_F32SUM><<<GB, blk, 0, stream>>>(
        tgt, query_pos, WT_oa, b_oa, S_oa, nullptr, nullptr, nullptr, nullptr, ROWS);
    // 4. attn_out = deform-sample (softmax fused)
    deform_sample<<<ROWS * 8 / 32, blk, 0, stream>>>(bf2, S_oa, refp, bf0);
    // 5. t = LN(tgt + attn_out @ Wc + bc)
    mfma_gemm<16, EP_RES_LN_BF, AM_BF16><<<GB, blk, 0, stream>>>(
        bf0, nullptr, WT_c, bc, bf1, tgt, nullptr, g_n1, b_n1, ROWS);
    // 6. out = LN(t + gelu(t @ W_ff + b_ff))
    mfma_gemm<16, EP_GELU_RES_LN_F32, AM_BF16><<<GB, blk, 0, stream>>>(
        bf1, nullptr, WT_ff, b_ff, out, bf1, nullptr, g_n3, b_n3, ROWS);
}

// Round 4
// 332.716 us; speedup vs baseline: 1.8011x; 1.0428x over previous
//
#include <hip/hip_runtime.h>
#include <hip/hip_bf16.h>
#include <math.h>

#define LQ   15000
#define LS_  15000
#define NB   2
#define ROWS (NB*LQ)   // 30000
#define HGT  100
#define WID  150

typedef __attribute__((ext_vector_type(8))) short bf16x8;
typedef __attribute__((ext_vector_type(4))) float f32x4;

__device__ inline short f2bf(float x) {
    __hip_bfloat16 h = __float2bfloat16(x);
    return *reinterpret_cast<short*>(&h);
}
__device__ inline unsigned pack2bf(float a, float b) {
    return ((unsigned)(unsigned short)f2bf(a)) | (((unsigned)(unsigned short)f2bf(b)) << 16);
}
__device__ inline float bf2f(short s) {
    return __uint_as_float(((unsigned)(unsigned short)s) << 16);
}
__device__ inline float gelu_exact(float x) {
    return 0.5f * x * (1.f + erff(x * 0.70710678118654752440f));
}

// ================================================================
// fused2<0>: value = mask(LN(src@W1+b1) @ W2 + b2)  (head-major out)
// fused2<1>: out  = LN2(t + gelu(t@W2+b2)), t = LN1(tgt + A@W1+b1)  (f32 out)
// Block: 64 rows x 256 cols, 4 waves, wave owns 16 full rows (LN-friendly).
// Intermediate row-tile T stays in LDS.
// ================================================================
template<int MODE>
__global__ __launch_bounds__(256) void fused2(
    const void* __restrict__ Ap,
    const short* __restrict__ W1T, const float* __restrict__ bias1,
    const float* __restrict__ res1,
    const float* __restrict__ g1v, const float* __restrict__ b1v,
    const short* __restrict__ W2T, const float* __restrict__ bias2,
    void* __restrict__ Out,
    const unsigned char* __restrict__ mask,
    const float* __restrict__ g2v, const float* __restrict__ b2v,
    int M)
{
    __shared__ short As[64][40];
    __shared__ short Bs[256][40];
    __shared__ short T[64][264];
    __shared__ float s_b1[256], s_g1[256], s_bb1[256], s_b2[256], s_g2[256], s_bb2[256];

    const int tid = threadIdx.x;
    const int bm0 = blockIdx.x * 64;
    const int wave = tid >> 6, lane = tid & 63;
    const int quad = lane >> 4, c = lane & 15;

    s_b1[tid] = bias1[tid];
    s_g1[tid] = g1v[tid]; s_bb1[tid] = b1v[tid];
    s_b2[tid] = bias2[tid];
    if (MODE == 1) { s_g2[tid] = g2v[tid]; s_bb2[tid] = b2v[tid]; }

    f32x4 acc[16];
    #pragma unroll
    for (int t = 0; t < 16; ++t) acc[t] = (f32x4){0.f, 0.f, 0.f, 0.f};

    // ---------------- phase 1: A @ W1 ----------------
    for (int k0 = 0; k0 < 256; k0 += 32) {
        if (MODE == 0) {
            const float* A = (const float*)Ap;
            #pragma unroll
            for (int it = 0; it < 2; ++it) {
                int f = it * 256 + tid; int m = f >> 3; int ko = (f & 7) * 4;
                int r = bm0 + m; if (r > M - 1) r = M - 1;
                float4 v = *(const float4*)&A[(size_t)r * 256 + k0 + ko];
                int2 p; p.x = pack2bf(v.x, v.y); p.y = pack2bf(v.z, v.w);
                *(int2*)&As[m][ko] = p;
            }
        } else {
            const short* A = (const short*)Ap;
            int m = tid >> 2; int ko = (tid & 3) * 8;
            int r = bm0 + m; if (r > M - 1) r = M - 1;
            *(int4*)&As[m][ko] = *(const int4*)&A[(size_t)r * 256 + k0 + ko];
        }
        #pragma unroll
        for (int it = 0; it < 4; ++it) {
            int f = it * 256 + tid; int n = f >> 2; int ko = (f & 3) * 8;
            *(int4*)&Bs[n][ko] = *(const int4*)&W1T[(size_t)n * 256 + k0 + ko];
        }
        __syncthreads();
        bf16x8 a = *(const bf16x8*)&As[wave * 16 + c][quad * 8];
        #pragma unroll
        for (int t = 0; t < 16; ++t) {
            bf16x8 b = *(const bf16x8*)&Bs[t * 16 + c][quad * 8];
            acc[t] = __builtin_amdgcn_mfma_f32_16x16x32_bf16(a, b, acc[t], 0, 0, 0);
        }
        __syncthreads();
    }

    // ---------------- epilogue 1: (+res) LN -> T (bf16, LDS) ----------------
    {
        const int rb = wave * 16 + quad * 4;
        #pragma unroll
        for (int reg = 0; reg < 4; ++reg) {
            int rloc = rb + reg;
            int rg = bm0 + rloc; int rgl = (rg < M) ? rg : (M - 1);
            float s = 0.f, sq = 0.f;
            float vv[16];
            #pragma unroll
            for (int t = 0; t < 16; ++t) {
                float v = acc[t][reg] + s_b1[t * 16 + c];
                if (MODE == 1) v += res1[(size_t)rgl * 256 + t * 16 + c];
                vv[t] = v; s += v; sq += v * v;
            }
            #pragma unroll
            for (int o = 1; o < 16; o <<= 1) {
                s += __shfl_xor(s, o, 64); sq += __shfl_xor(sq, o, 64);
            }
            float mean = s * (1.f / 256.f);
            float var  = sq * (1.f / 256.f) - mean * mean;
            float rs   = rsqrtf(var + 1e-5f);
            #pragma unroll
            for (int t = 0; t < 16; ++t)
                T[rloc][t * 16 + c] = f2bf((vv[t] - mean) * rs * s_g1[t * 16 + c] + s_bb1[t * 16 + c]);
        }
    }
    __syncthreads();

    // ---------------- phase 2: T @ W2 (A from LDS) ----------------
    #pragma unroll
    for (int t = 0; t < 16; ++t) acc[t] = (f32x4){0.f, 0.f, 0.f, 0.f};
    for (int k0 = 0; k0 < 256; k0 += 32) {
        #pragma unroll
        for (int it = 0; it < 4; ++it) {
            int f = it * 256 + tid; int n = f >> 2; int ko = (f & 3) * 8;
            *(int4*)&Bs[n][ko] = *(const int4*)&W2T[(size_t)n * 256 + k0 + ko];
        }
        __syncthreads();
        bf16x8 a = *(const bf16x8*)&T[wave * 16 + c][k0 + quad * 8];
        #pragma unroll
        for (int t = 0; t < 16; ++t) {
            bf16x8 b = *(const bf16x8*)&Bs[t * 16 + c][quad * 8];
            acc[t] = __builtin_amdgcn_mfma_f32_16x16x32_bf16(a, b, acc[t], 0, 0, 0);
        }
        __syncthreads();
    }

    // ---------------- epilogue 2 ----------------
    const int rb = wave * 16 + quad * 4;
    if constexpr (MODE == 0) {
        short* O = (short*)Out;
        #pragma unroll
        for (int reg = 0; reg < 4; ++reg) {
            int rloc = rb + reg; int r = bm0 + rloc;
            if (r < M) {
                float mz = mask[r] ? 0.f : 1.f;
                int n = (r >= LS_) ? 1 : 0;
                int sidx = r - n * LS_;
                #pragma unroll
                for (int t = 0; t < 16; ++t) {
                    int col = t * 16 + c; int h = col >> 5, d = col & 31;
                    O[(((size_t)n * 8 + h) * LS_ + sidx) * 32 + d] =
                        f2bf((acc[t][reg] + s_b2[col]) * mz);
                }
            }
        }
    } else {
        float* O = (float*)Out;
        #pragma unroll
        for (int reg = 0; reg < 4; ++reg) {
            int rloc = rb + reg; int r = bm0 + rloc;
            float s = 0.f, sq = 0.f;
            float vv[16];
            #pragma unroll
            for (int t = 0; t < 16; ++t) {
                int col = t * 16 + c;
                float v = gelu_exact(acc[t][reg] + s_b2[col]) + bf2f(T[rloc][col]);
                vv[t] = v; s += v; sq += v * v;
            }
            #pragma unroll
            for (int o = 1; o < 16; o <<= 1) {
                s += __shfl_xor(s, o, 64); sq += __shfl_xor(sq, o, 64);
            }
            float mean = s * (1.f / 256.f);
            float var  = sq * (1.f / 256.f) - mean * mean;
            float rs   = rsqrtf(var + 1e-5f);
            if (r < M) {
                #pragma unroll
                for (int t = 0; t < 16; ++t) {
                    int col = t * 16 + c;
                    O[(size_t)r * 256 + col] = (vv[t] - mean) * rs * s_g2[col] + s_bb2[col];
                }
            }
        }
    }
}

// ================================================================
// fused_oa_sample: S = (tgt+qpos)@[W_off|W_attn]+b (LDS), then
// softmax over 4 logits + bilinear gather from head-major value.
// ================================================================
__global__ __launch_bounds__(256) void fused_oa_sample(
    const float* __restrict__ tgt, const float* __restrict__ qpos,
    const short* __restrict__ WToa, const float* __restrict__ b_oa,
    const short* __restrict__ value,   // [NB][8][LS_][32] bf16
    const float* __restrict__ refp,    // [ROWS,2]
    short* __restrict__ out, int M)    // [ROWS,256] bf16
{
    __shared__ short As[64][40];
    __shared__ short Bs[96][40];
    __shared__ float Ss[64][100];
    __shared__ float sb[96];

    const int tid = threadIdx.x;
    const int bm0 = blockIdx.x * 64;
    const int wave = tid >> 6, lane = tid & 63;
    const int quad = lane >> 4, c = lane & 15;

    if (tid < 96) sb[tid] = b_oa[tid];

    f32x4 acc[6];
    #pragma unroll
    for (int t = 0; t < 6; ++t) acc[t] = (f32x4){0.f, 0.f, 0.f, 0.f};

    for (int k0 = 0; k0 < 256; k0 += 32) {
        #pragma unroll
        for (int it = 0; it < 2; ++it) {
            int f = it * 256 + tid; int m = f >> 3; int ko = (f & 7) * 4;
            int r = bm0 + m; if (r > M - 1) r = M - 1;
            float4 v = *(const float4*)&tgt[(size_t)r * 256 + k0 + ko];
            float4 w = *(const float4*)&qpos[(size_t)r * 256 + k0 + ko];
            v.x += w.x; v.y += w.y; v.z += w.z; v.w += w.w;
            int2 p; p.x = pack2bf(v.x, v.y); p.y = pack2bf(v.z, v.w);
            *(int2*)&As[m][ko] = p;
        }
        #pragma unroll
        for (int it = 0; it < 2; ++it) {
            int f = it * 256 + tid;
            if (f < 384) {
                int n = f >> 2; int ko = (f & 3) * 8;
                *(int4*)&Bs[n][ko] = *(const int4*)&WToa[(size_t)n * 256 + k0 + ko];
            }
        }
        __syncthreads();
        bf16x8 a = *(const bf16x8*)&As[wave * 16 + c][quad * 8];
        #pragma unroll
        for (int t = 0; t < 6; ++t) {
            bf16x8 b = *(const bf16x8*)&Bs[t * 16 + c][quad * 8];
            acc[t] = __builtin_amdgcn_mfma_f32_16x16x32_bf16(a, b, acc[t], 0, 0, 0);
        }
        __syncthreads();
    }
    // epilogue -> Ss
    {
        const int rbq = wave * 16 + quad * 4;
        #pragma unroll
        for (int reg = 0; reg < 4; ++reg) {
            int rloc = rbq + reg;
            #pragma unroll
            for (int t = 0; t < 6; ++t)
                Ss[rloc][t * 16 + c] = acc[t][reg] + sb[t * 16 + c];
        }
    }
    __syncthreads();

    // ---------------- sampling: 512 groups (64 rows x 8 heads), 8 lanes each ----------------
    const int c4 = tid & 7;
    #pragma unroll 2
    for (int it = 0; it < 16; ++it) {
        int g = it * 32 + (tid >> 3);
        int rloc = g >> 3, h = g & 7;
        int r = bm0 + rloc;
        bool ok = r < M;
        int rr = ok ? r : (M - 1);
        int n = (rr >= LS_) ? 1 : 0;
        float rx = refp[(size_t)rr * 2 + 0], ry = refp[(size_t)rr * 2 + 1];
        float4 oA = *(const float4*)&Ss[rloc][h * 8];
        float4 oB = *(const float4*)&Ss[rloc][h * 8 + 4];
        float4 lg = *(const float4*)&Ss[rloc][64 + h * 4];

        float mx = fmaxf(fmaxf(lg.x, lg.y), fmaxf(lg.z, lg.w));
        float e0 = expf(lg.x - mx), e1 = expf(lg.y - mx), e2 = expf(lg.z - mx), e3 = expf(lg.w - mx);
        float inv = 1.f / (e0 + e1 + e2 + e3);
        float aw[4] = {e0 * inv, e1 * inv, e2 * inv, e3 * inv};
        float ox[4] = {oA.x, oA.z, oB.x, oB.z};
        float oy[4] = {oA.y, oA.w, oB.y, oB.w};

        const short* vb = value + (((size_t)n * 8 + h) * LS_) * 32 + c4 * 4;
        float a0 = 0.f, a1 = 0.f, a2 = 0.f, a3 = 0.f;
        #pragma unroll
        for (int p = 0; p < 4; ++p) {
            float x = rx * (float)WID + ox[p] - 0.5f;
            float y = ry * (float)HGT + oy[p] - 0.5f;
            float x0f = floorf(x), y0f = floorf(y);
            float lx = x - x0f, ly = y - y0f;
            int x0 = (int)x0f, y0 = (int)y0f;
            int x1 = x0 + 1, y1 = y0 + 1;
            bool vx0 = (x0 >= 0) & (x0 < WID), vx1 = (x1 >= 0) & (x1 < WID);
            bool vy0 = (y0 >= 0) & (y0 < HGT), vy1 = (y1 >= 0) & (y1 < HGT);
            float w00 = (vx0 & vy0) ? (1.f - lx) * (1.f - ly) * aw[p] : 0.f;
            float w10 = (vx1 & vy0) ? lx * (1.f - ly) * aw[p] : 0.f;
            float w01 = (vx0 & vy1) ? (1.f - lx) * ly * aw[p] : 0.f;
            float w11 = (vx1 & vy1) ? lx * ly * aw[p] : 0.f;
            int xc0 = min(max(x0, 0), WID - 1), xc1 = min(max(x1, 0), WID - 1);
            int yc0 = min(max(y0, 0), HGT - 1), yc1 = min(max(y1, 0), HGT - 1);
            int2 v00 = *(const int2*)&vb[(size_t)(yc0 * WID + xc0) * 32];
            int2 v10 = *(const int2*)&vb[(size_t)(yc0 * WID + xc1) * 32];
            int2 v01 = *(const int2*)&vb[(size_t)(yc1 * WID + xc0) * 32];
            int2 v11 = *(const int2*)&vb[(size_t)(yc1 * WID + xc1) * 32];
            a0 += w00 * __uint_as_float(((unsigned)v00.x) << 16)
                + w10 * __uint_as_float(((unsigned)v10.x) << 16)
                + w01 * __uint_as_float(((unsigned)v01.x) << 16)
                + w11 * __uint_as_float(((unsigned)v11.x) << 16);
            a1 += w00 * __uint_as_float(v00.x & 0xffff0000u)
                + w10 * __uint_as_float(v10.x & 0xffff0000u)
                + w01 * __uint_as_float(v01.x & 0xffff0000u)
                + w11 * __uint_as_float(v11.x & 0xffff0000u);
            a2 += w00 * __uint_as_float(((unsigned)v00.y) << 16)
                + w10 * __uint_as_float(((unsigned)v10.y) << 16)
                + w01 * __uint_as_float(((unsigned)v01.y) << 16)
                + w11 * __uint_as_float(((unsigned)v11.y) << 16);
            a3 += w00 * __uint_as_float(v00.y & 0xffff0000u)
                + w10 * __uint_as_float(v10.y & 0xffff0000u)
                + w01 * __uint_as_float(v01.y & 0xffff0000u)
                + w11 * __uint_as_float(v11.y & 0xffff0000u);
        }
        if (ok) {
            int2 o;
            o.x = pack2bf(a0, a1);
            o.y = pack2bf(a2, a3);
            *(int2*)&out[(size_t)r * 256 + h * 32 + c4 * 4] = o;
        }
    }
}

// ================================================================
// prep_all: all weight prep in one dispatch (401 blocks)
// ================================================================
__global__ __launch_bounds__(256) void prep_all(
    const float* __restrict__ W_dsa, const float* __restrict__ W_val,
    const float* __restrict__ W_ff,  const float* __restrict__ W_out,
    const float* __restrict__ W_csa, const float* __restrict__ b_out,
    const float* __restrict__ b_csa, const float* __restrict__ W_off,
    const float* __restrict__ W_attn, const float* __restrict__ b_off,
    const float* __restrict__ b_attn,
    short* __restrict__ WT_dsa, short* __restrict__ WT_val, short* __restrict__ WT_ff,
    short* __restrict__ WT_c, float* __restrict__ bc,
    short* __restrict__ WT_oa, float* __restrict__ b_oa)
{
    __shared__ float tile[64][65];
    const int b = blockIdx.x, tid = threadIdx.x;
    if (b < 48) {
        const float* W = (b < 16) ? W_dsa : (b < 32) ? W_val : W_ff;
        short* WT = (b < 16) ? WT_dsa : (b < 32) ? WT_val : WT_ff;
        int t = b & 15; int bx = (t & 3) * 64, by = (t >> 2) * 64;
        #pragma unroll
        for (int it = 0; it < 4; ++it) {
            int f = it * 256 + tid; int i = f >> 4; int j = (f & 15) * 4;
            float4 v = *(const float4*)&W[(size_t)(by + i) * 256 + bx + j];
            tile[i][j] = v.x; tile[i][j + 1] = v.y; tile[i][j + 2] = v.z; tile[i][j + 3] = v.w;
        }
        __syncthreads();
        #pragma unroll
        for (int it = 0; it < 16; ++it) {
            int f = it * 256 + tid; int nl = f >> 6; int kl = f & 63;
            WT[(size_t)(bx + nl) * 256 + by + kl] = f2bf(tile[kl][nl]);
        }
    } else if (b < 304) {
        int k = b - 48, n = tid;
        float s = 0.f;
        for (int j = 0; j < 256; ++j)
            s = fmaf(W_out[(size_t)k * 256 + j], W_csa[(size_t)j * 256 + n], s);
        WT_c[(size_t)n * 256 + k] = f2bf(s);
    } else if (b == 304) {
        int j = tid;
        float s = b_csa[j];
        for (int k = 0; k < 256; ++k)
            s = fmaf(b_out[k], W_csa[(size_t)k * 256 + j], s);
        bc[j] = s;
    } else {
        int j = b - 305, k = tid;
        float v = (j < 64) ? W_off[(size_t)k * 64 + j] : W_attn[(size_t)k * 32 + (j - 64)];
        WT_oa[(size_t)j * 256 + k] = f2bf(v);
        if (k == 0) b_oa[j] = (j < 64) ? b_off[j] : b_attn[j - 64];
    }
}

// ================= launcher =================
extern "C" void kernel_launch(void* const* d_in, const int* in_sizes, int n_in,
                              void* d_out, int out_size, void* d_ws, size_t ws_size,
                              hipStream_t stream)
{
    const float* tgt       = (const float*)d_in[0];
    const float* query_pos = (const float*)d_in[1];
    const float* refp      = (const float*)d_in[4];
    const float* src       = (const float*)d_in[6];
    const unsigned char* mask = (const unsigned char*)d_in[9];
    const float* W_dsa  = (const float*)d_in[10]; const float* b_dsa  = (const float*)d_in[11];
    const float* g_nds  = (const float*)d_in[12]; const float* b_nds  = (const float*)d_in[13];
    const float* W_off  = (const float*)d_in[14]; const float* b_off  = (const float*)d_in[15];
    const float* W_attn = (const float*)d_in[16]; const float* b_attn = (const float*)d_in[17];
    const float* W_val  = (const float*)d_in[18]; const float* b_val  = (const float*)d_in[19];
    const float* W_out  = (const float*)d_in[20]; const float* b_out  = (const float*)d_in[21];
    const float* W_csa  = (const float*)d_in[22]; const float* b_csa  = (const float*)d_in[23];
    const float* g_n1   = (const float*)d_in[24]; const float* b_n1   = (const float*)d_in[25];
    const float* W_ff   = (const float*)d_in[26]; const float* b_ff   = (const float*)d_in[27];
    const float* g_n3   = (const float*)d_in[28]; const float* b_n3   = (const float*)d_in[29];
    float* out = (float*)d_out;

    short* attn_out = (short*)d_ws;                       // [30000*256] bf16
    short* value    = attn_out + (size_t)ROWS * 256;      // [30000*256] bf16 head-major
    short* WT_dsa   = value + (size_t)ROWS * 256;
    short* WT_val   = WT_dsa + 65536;
    short* WT_ff    = WT_val + 65536;
    short* WT_c     = WT_ff + 65536;
    short* WT_oa    = WT_c + 65536;                       // 96*256
    float* bc       = (float*)(WT_oa + 96 * 256);
    float* b_oa     = bc + 256;

    dim3 blk(256);
    const int GB = (ROWS + 63) / 64;   // 469

    prep_all<<<401, blk, 0, stream>>>(
        W_dsa, W_val, W_ff, W_out, W_csa, b_out, b_csa, W_off, W_attn, b_off, b_attn,
        WT_dsa, WT_val, WT_ff, WT_c, bc, WT_oa, b_oa);

    // value = mask(LN(src@W_dsa+b_dsa) @ W_val + b_val), head-major
    fused2<0><<<GB, blk, 0, stream>>>(
        src, WT_dsa, b_dsa, nullptr, g_nds, b_nds,
        WT_val, b_val, value, mask, nullptr, nullptr, ROWS);

    // attn_out = deform-sample(softmax((tgt+qpos)@W_attn), (tgt+qpos)@W_off, value)
    fused_oa_sample<<<GB, blk, 0, stream>>>(
        tgt, query_pos, WT_oa, b_oa, value, refp, attn_out, ROWS);

    // out = LN3(t + gelu(t@W_ff+b_ff)), t = LN1(tgt + attn_out@Wc+bc)
    fused2<1><<<GB, blk, 0, stream>>>(
        attn_out, WT_c, bc, tgt, g_n1, b_n1,
        WT_ff, b_ff, out, nullptr, g_n3, b_n3, ROWS);
}

// Round 5
// 319.981 us; speedup vs baseline: 1.8728x; 1.0398x over previous
//
#include <hip/hip_runtime.h>
#include <hip/hip_bf16.h>
#include <math.h>

#define LQ   15000
#define LS_  15000
#define NB   2
#define ROWS (NB*LQ)   // 30000
#define HGT  100
#define WID  150

typedef __attribute__((ext_vector_type(8))) short bf16x8;
typedef __attribute__((ext_vector_type(4))) float f32x4;

__device__ inline short f2bf(float x) {
    __hip_bfloat16 h = __float2bfloat16(x);
    return *reinterpret_cast<short*>(&h);
}
__device__ inline unsigned pack2bf(float a, float b) {
    return ((unsigned)(unsigned short)f2bf(a)) | (((unsigned)(unsigned short)f2bf(b)) << 16);
}
__device__ inline float bf2f(short s) {
    return __uint_as_float(((unsigned)(unsigned short)s) << 16);
}
__device__ inline float gelu_exact(float x) {
    return 0.5f * x * (1.f + erff(x * 0.70710678118654752440f));
}

// ================================================================
// fused2<0>: value = mask(LN(src@W1+b1) @ W2 + b2)  (head-major bf16 out)
// fused2<1>: out  = LN2(t + gelu(t@W2+b2)), t = LN1(tgt + A@W1+b1)  (f32 out)
// Block: 64 rows x 256 cols, 4 waves; wave owns 16 full rows.
// LDS = Bs(20480) + [T(33792) overlaying As(5120)] = 54272 B -> 3 blocks/CU.
// Biases/LN params read from global in epilogues (L2-hot) to keep LDS small.
// ================================================================
template<int MODE>
__global__ __launch_bounds__(256, 3) void fused2(
    const void* __restrict__ Ap,
    const short* __restrict__ W1T, const float* __restrict__ bias1,
    const float* __restrict__ res1,
    const float* __restrict__ g1v, const float* __restrict__ b1v,
    const short* __restrict__ W2T, const float* __restrict__ bias2,
    void* __restrict__ Out,
    const unsigned char* __restrict__ mask,
    const float* __restrict__ g2v, const float* __restrict__ b2v,
    int M)
{
    __shared__ __align__(16) char lds[54272];
    short (*Bs)[40]  = (short(*)[40])lds;            // 256 x 40 shorts = 20480 B
    short (*T)[264]  = (short(*)[264])(lds + 20480); // 64 x 264 shorts = 33792 B
    short (*As)[40]  = (short(*)[40])(lds + 20480);  // overlay inside T region (phase 1 only)

    const int tid = threadIdx.x;
    const int bm0 = blockIdx.x * 64;
    const int wave = tid >> 6, lane = tid & 63;
    const int quad = lane >> 4, c = lane & 15;

    f32x4 acc[16];
    #pragma unroll
    for (int t = 0; t < 16; ++t) acc[t] = (f32x4){0.f, 0.f, 0.f, 0.f};

    // ---------------- phase 1: A @ W1 ----------------
    for (int k0 = 0; k0 < 256; k0 += 32) {
        if (MODE == 0) {
            const float* A = (const float*)Ap;
            #pragma unroll
            for (int it = 0; it < 2; ++it) {
                int f = it * 256 + tid; int m = f >> 3; int ko = (f & 7) * 4;
                int r = bm0 + m; if (r > M - 1) r = M - 1;
                float4 v = *(const float4*)&A[(size_t)r * 256 + k0 + ko];
                int2 p; p.x = pack2bf(v.x, v.y); p.y = pack2bf(v.z, v.w);
                *(int2*)&As[m][ko] = p;
            }
        } else {
            const short* A = (const short*)Ap;
            int m = tid >> 2; int ko = (tid & 3) * 8;
            int r = bm0 + m; if (r > M - 1) r = M - 1;
            *(int4*)&As[m][ko] = *(const int4*)&A[(size_t)r * 256 + k0 + ko];
        }
        #pragma unroll
        for (int it = 0; it < 4; ++it) {
            int f = it * 256 + tid; int n = f >> 2; int ko = (f & 3) * 8;
            *(int4*)&Bs[n][ko] = *(const int4*)&W1T[(size_t)n * 256 + k0 + ko];
        }
        __syncthreads();
        bf16x8 a = *(const bf16x8*)&As[wave * 16 + c][quad * 8];
        #pragma unroll
        for (int t = 0; t < 16; ++t) {
            bf16x8 b = *(const bf16x8*)&Bs[t * 16 + c][quad * 8];
            acc[t] = __builtin_amdgcn_mfma_f32_16x16x32_bf16(a, b, acc[t], 0, 0, 0);
        }
        __syncthreads();
    }
    // After the trailing barrier all As reads are drained -> safe to overwrite with T.

    // ---------------- epilogue 1: (+res) LN -> T (bf16, LDS, own-wave rows) ----------------
    {
        const int rb = wave * 16 + quad * 4;
        #pragma unroll
        for (int reg = 0; reg < 4; ++reg) {
            int rloc = rb + reg;
            int rg = bm0 + rloc; int rgl = (rg < M) ? rg : (M - 1);
            float s = 0.f, sq = 0.f;
            float vv[16];
            #pragma unroll
            for (int t = 0; t < 16; ++t) {
                int col = t * 16 + c;
                float v = acc[t][reg] + bias1[col];
                if (MODE == 1) v += res1[(size_t)rgl * 256 + col];
                vv[t] = v; s += v; sq += v * v;
            }
            #pragma unroll
            for (int o = 1; o < 16; o <<= 1) {
                s += __shfl_xor(s, o, 64); sq += __shfl_xor(sq, o, 64);
            }
            float mean = s * (1.f / 256.f);
            float var  = sq * (1.f / 256.f) - mean * mean;
            float rs   = rsqrtf(var + 1e-5f);
            #pragma unroll
            for (int t = 0; t < 16; ++t) {
                int col = t * 16 + c;
                T[rloc][col] = f2bf((vv[t] - mean) * rs * g1v[col] + b1v[col]);
            }
        }
    }
    // No barrier needed: each wave reads back only the T rows it wrote (in-order LDS).

    // ---------------- phase 2: T @ W2 ----------------
    #pragma unroll
    for (int t = 0; t < 16; ++t) acc[t] = (f32x4){0.f, 0.f, 0.f, 0.f};
    for (int k0 = 0; k0 < 256; k0 += 32) {
        #pragma unroll
        for (int it = 0; it < 4; ++it) {
            int f = it * 256 + tid; int n = f >> 2; int ko = (f & 3) * 8;
            *(int4*)&Bs[n][ko] = *(const int4*)&W2T[(size_t)n * 256 + k0 + ko];
        }
        __syncthreads();
        bf16x8 a = *(const bf16x8*)&T[wave * 16 + c][k0 + quad * 8];
        #pragma unroll
        for (int t = 0; t < 16; ++t) {
            bf16x8 b = *(const bf16x8*)&Bs[t * 16 + c][quad * 8];
            acc[t] = __builtin_amdgcn_mfma_f32_16x16x32_bf16(a, b, acc[t], 0, 0, 0);
        }
        __syncthreads();
    }

    // ---------------- epilogue 2 ----------------
    const int rb = wave * 16 + quad * 4;
    if constexpr (MODE == 0) {
        short* O = (short*)Out;
        #pragma unroll
        for (int reg = 0; reg < 4; ++reg) {
            int rloc = rb + reg; int r = bm0 + rloc;
            if (r < M) {
                float mz = mask[r] ? 0.f : 1.f;
                int n = (r >= LS_) ? 1 : 0;
                int sidx = r - n * LS_;
                #pragma unroll
                for (int t = 0; t < 16; ++t) {
                    int col = t * 16 + c; int h = col >> 5, d = col & 31;
                    O[(((size_t)n * 8 + h) * LS_ + sidx) * 32 + d] =
                        f2bf((acc[t][reg] + bias2[col]) * mz);
                }
            }
        }
    } else {
        float* O = (float*)Out;
        #pragma unroll
        for (int reg = 0; reg < 4; ++reg) {
            int rloc = rb + reg; int r = bm0 + rloc;
            float s = 0.f, sq = 0.f;
            float vv[16];
            #pragma unroll
            for (int t = 0; t < 16; ++t) {
                int col = t * 16 + c;
                float v = gelu_exact(acc[t][reg] + bias2[col]) + bf2f(T[rloc][col]);
                vv[t] = v; s += v; sq += v * v;
            }
            #pragma unroll
            for (int o = 1; o < 16; o <<= 1) {
                s += __shfl_xor(s, o, 64); sq += __shfl_xor(sq, o, 64);
            }
            float mean = s * (1.f / 256.f);
            float var  = sq * (1.f / 256.f) - mean * mean;
            float rs   = rsqrtf(var + 1e-5f);
            if (r < M) {
                #pragma unroll
                for (int t = 0; t < 16; ++t) {
                    int col = t * 16 + c;
                    O[(size_t)r * 256 + col] = (vv[t] - mean) * rs * g2v[col] + b2v[col];
                }
            }
        }
    }
}

// ================================================================
// oa_gemm: S_oa = (tgt+qpos) @ [W_off|W_attn] + b   (f32 out, [ROWS,96])
// Slim LDS (~12.5 KB) -> high occupancy.
// ================================================================
__global__ __launch_bounds__(256) void oa_gemm(
    const float* __restrict__ tgt, const float* __restrict__ qpos,
    const short* __restrict__ WToa, const float* __restrict__ b_oa,
    float* __restrict__ S_oa, int M)
{
    __shared__ short As[64][40];
    __shared__ short Bs[96][40];
    __shared__ float sb[96];

    const int tid = threadIdx.x;
    const int bm0 = blockIdx.x * 64;
    const int wave = tid >> 6, lane = tid & 63;
    const int quad = lane >> 4, c = lane & 15;

    if (tid < 96) sb[tid] = b_oa[tid];

    f32x4 acc[6];
    #pragma unroll
    for (int t = 0; t < 6; ++t) acc[t] = (f32x4){0.f, 0.f, 0.f, 0.f};

    for (int k0 = 0; k0 < 256; k0 += 32) {
        #pragma unroll
        for (int it = 0; it < 2; ++it) {
            int f = it * 256 + tid; int m = f >> 3; int ko = (f & 7) * 4;
            int r = bm0 + m; if (r > M - 1) r = M - 1;
            float4 v = *(const float4*)&tgt[(size_t)r * 256 + k0 + ko];
            float4 w = *(const float4*)&qpos[(size_t)r * 256 + k0 + ko];
            v.x += w.x; v.y += w.y; v.z += w.z; v.w += w.w;
            int2 p; p.x = pack2bf(v.x, v.y); p.y = pack2bf(v.z, v.w);
            *(int2*)&As[m][ko] = p;
        }
        {
            int f = tid;
            if (f < 192) { /* 96 rows x 4 chunks = 384; two waves cover it */ }
            #pragma unroll
            for (int it = 0; it < 2; ++it) {
                int ff = it * 256 + tid;
                if (ff < 384) {
                    int n = ff >> 2; int ko = (ff & 3) * 8;
                    *(int4*)&Bs[n][ko] = *(const int4*)&WToa[(size_t)n * 256 + k0 + ko];
                }
            }
        }
        __syncthreads();
        bf16x8 a = *(const bf16x8*)&As[wave * 16 + c][quad * 8];
        #pragma unroll
        for (int t = 0; t < 6; ++t) {
            bf16x8 b = *(const bf16x8*)&Bs[t * 16 + c][quad * 8];
            acc[t] = __builtin_amdgcn_mfma_f32_16x16x32_bf16(a, b, acc[t], 0, 0, 0);
        }
        __syncthreads();
    }

    const int rb = wave * 16 + quad * 4;
    #pragma unroll
    for (int reg = 0; reg < 4; ++reg) {
        int r = bm0 + rb + reg;
        if (r < M) {
            #pragma unroll
            for (int t = 0; t < 6; ++t)
                S_oa[(size_t)r * 96 + t * 16 + c] = acc[t][reg] + sb[t * 16 + c];
        }
    }
}

// ================================================================
// deform_sample: 8 lanes per (r,h), 4 channels/lane; 7500 blocks for TLP.
// ================================================================
__global__ __launch_bounds__(256) void deform_sample(
    const short* __restrict__ value,   // [NB][8][LS_][32] bf16, head-major
    const float* __restrict__ S_oa,    // [ROWS, 96]
    const float* __restrict__ refp,    // [ROWS, 2]
    short* __restrict__ out)           // [ROWS, 256] bf16
{
    int grp = blockIdx.x * 32 + (threadIdx.x >> 3);
    int c4  = threadIdx.x & 7;
    int h = grp & 7;
    int r = grp >> 3;
    int n = (r >= LS_) ? 1 : 0;

    const float* row = S_oa + (size_t)r * 96;
    float rx = refp[(size_t)r * 2 + 0], ry = refp[(size_t)r * 2 + 1];
    float4 oA = *(const float4*)&row[h * 8];
    float4 oB = *(const float4*)&row[h * 8 + 4];
    float4 lg = *(const float4*)&row[64 + h * 4];

    float mx = fmaxf(fmaxf(lg.x, lg.y), fmaxf(lg.z, lg.w));
    float e0 = expf(lg.x - mx), e1 = expf(lg.y - mx), e2 = expf(lg.z - mx), e3 = expf(lg.w - mx);
    float inv = 1.f / (e0 + e1 + e2 + e3);
    float aw[4] = {e0 * inv, e1 * inv, e2 * inv, e3 * inv};
    float ox[4] = {oA.x, oA.z, oB.x, oB.z};
    float oy[4] = {oA.y, oA.w, oB.y, oB.w};

    const short* vb = value + (((size_t)n * 8 + h) * LS_) * 32 + c4 * 4;
    float a0 = 0.f, a1 = 0.f, a2 = 0.f, a3 = 0.f;

    #pragma unroll
    for (int p = 0; p < 4; ++p) {
        float x = rx * (float)WID + ox[p] - 0.5f;
        float y = ry * (float)HGT + oy[p] - 0.5f;
        float x0f = floorf(x), y0f = floorf(y);
        float lx = x - x0f, ly = y - y0f;
        int x0 = (int)x0f, y0 = (int)y0f;
        int x1 = x0 + 1, y1 = y0 + 1;
        bool vx0 = (x0 >= 0) & (x0 < WID), vx1 = (x1 >= 0) & (x1 < WID);
        bool vy0 = (y0 >= 0) & (y0 < HGT), vy1 = (y1 >= 0) & (y1 < HGT);
        float w00 = (vx0 & vy0) ? (1.f - lx) * (1.f - ly) * aw[p] : 0.f;
        float w10 = (vx1 & vy0) ? lx * (1.f - ly) * aw[p] : 0.f;
        float w01 = (vx0 & vy1) ? (1.f - lx) * ly * aw[p] : 0.f;
        float w11 = (vx1 & vy1) ? lx * ly * aw[p] : 0.f;
        int xc0 = min(max(x0, 0), WID - 1), xc1 = min(max(x1, 0), WID - 1);
        int yc0 = min(max(y0, 0), HGT - 1), yc1 = min(max(y1, 0), HGT - 1);
        int2 v00 = *(const int2*)&vb[(size_t)(yc0 * WID + xc0) * 32];
        int2 v10 = *(const int2*)&vb[(size_t)(yc0 * WID + xc1) * 32];
        int2 v01 = *(const int2*)&vb[(size_t)(yc1 * WID + xc0) * 32];
        int2 v11 = *(const int2*)&vb[(size_t)(yc1 * WID + xc1) * 32];
        a0 += w00 * __uint_as_float(((unsigned)v00.x) << 16)
            + w10 * __uint_as_float(((unsigned)v10.x) << 16)
            + w01 * __uint_as_float(((unsigned)v01.x) << 16)
            + w11 * __uint_as_float(((unsigned)v11.x) << 16);
        a1 += w00 * __uint_as_float(v00.x & 0xffff0000u)
            + w10 * __uint_as_float(v10.x & 0xffff0000u)
            + w01 * __uint_as_float(v01.x & 0xffff0000u)
            + w11 * __uint_as_float(v11.x & 0xffff0000u);
        a2 += w00 * __uint_as_float(((unsigned)v00.y) << 16)
            + w10 * __uint_as_float(((unsigned)v10.y) << 16)
            + w01 * __uint_as_float(((unsigned)v01.y) << 16)
            + w11 * __uint_as_float(((unsigned)v11.y) << 16);
        a3 += w00 * __uint_as_float(v00.y & 0xffff0000u)
            + w10 * __uint_as_float(v10.y & 0xffff0000u)
            + w01 * __uint_as_float(v01.y & 0xffff0000u)
            + w11 * __uint_as_float(v11.y & 0xffff0000u);
    }
    int2 o;
    o.x = pack2bf(a0, a1);
    o.y = pack2bf(a2, a3);
    *(int2*)&out[(size_t)r * 256 + h * 32 + c4 * 4] = o;
}

// ================================================================
// prep_all: all weight prep in one dispatch (401 blocks)
// ================================================================
__global__ __launch_bounds__(256) void prep_all(
    const float* __restrict__ W_dsa, const float* __restrict__ W_val,
    const float* __restrict__ W_ff,  const float* __restrict__ W_out,
    const float* __restrict__ W_csa, const float* __restrict__ b_out,
    const float* __restrict__ b_csa, const float* __restrict__ W_off,
    const float* __restrict__ W_attn, const float* __restrict__ b_off,
    const float* __restrict__ b_attn,
    short* __restrict__ WT_dsa, short* __restrict__ WT_val, short* __restrict__ WT_ff,
    short* __restrict__ WT_c, float* __restrict__ bc,
    short* __restrict__ WT_oa, float* __restrict__ b_oa)
{
    __shared__ float tile[64][65];
    const int b = blockIdx.x, tid = threadIdx.x;
    if (b < 48) {
        const float* W = (b < 16) ? W_dsa : (b < 32) ? W_val : W_ff;
        short* WT = (b < 16) ? WT_dsa : (b < 32) ? WT_val : WT_ff;
        int t = b & 15; int bx = (t & 3) * 64, by = (t >> 2) * 64;
        #pragma unroll
        for (int it = 0; it < 4; ++it) {
            int f = it * 256 + tid; int i = f >> 4; int j = (f & 15) * 4;
            float4 v = *(const float4*)&W[(size_t)(by + i) * 256 + bx + j];
            tile[i][j] = v.x; tile[i][j + 1] = v.y; tile[i][j + 2] = v.z; tile[i][j + 3] = v.w;
        }
        __syncthreads();
        #pragma unroll
        for (int it = 0; it < 16; ++it) {
            int f = it * 256 + tid; int nl = f >> 6; int kl = f & 63;
            WT[(size_t)(bx + nl) * 256 + by + kl] = f2bf(tile[kl][nl]);
        }
    } else if (b < 304) {
        int k = b - 48, n = tid;
        float s = 0.f;
        #pragma unroll 8
        for (int j = 0; j < 256; ++j)
            s = fmaf(W_out[(size_t)k * 256 + j], W_csa[(size_t)j * 256 + n], s);
        WT_c[(size_t)n * 256 + k] = f2bf(s);
    } else if (b == 304) {
        int j = tid;
        float s = b_csa[j];
        #pragma unroll 8
        for (int k = 0; k < 256; ++k)
            s = fmaf(b_out[k], W_csa[(size_t)k * 256 + j], s);
        bc[j] = s;
    } else {
        int j = b - 305, k = tid;
        float v = (j < 64) ? W_off[(size_t)k * 64 + j] : W_attn[(size_t)k * 32 + (j - 64)];
        WT_oa[(size_t)j * 256 + k] = f2bf(v);
        if (k == 0) b_oa[j] = (j < 64) ? b_off[j] : b_attn[j - 64];
    }
}

// ================= launcher =================
extern "C" void kernel_launch(void* const* d_in, const int* in_sizes, int n_in,
                              void* d_out, int out_size, void* d_ws, size_t ws_size,
                              hipStream_t stream)
{
    const float* tgt       = (const float*)d_in[0];
    const float* query_pos = (const float*)d_in[1];
    const float* refp      = (const float*)d_in[4];
    const float* src       = (const float*)d_in[6];
    const unsigned char* mask = (const unsigned char*)d_in[9];
    const float* W_dsa  = (const float*)d_in[10]; const float* b_dsa  = (const float*)d_in[11];
    const float* g_nds  = (const float*)d_in[12]; const float* b_nds  = (const float*)d_in[13];
    const float* W_off  = (const float*)d_in[14]; const float* b_off  = (const float*)d_in[15];
    const float* W_attn = (const float*)d_in[16]; const float* b_attn = (const float*)d_in[17];
    const float* W_val  = (const float*)d_in[18]; const float* b_val  = (const float*)d_in[19];
    const float* W_out  = (const float*)d_in[20]; const float* b_out  = (const float*)d_in[21];
    const float* W_csa  = (const float*)d_in[22]; const float* b_csa  = (const float*)d_in[23];
    const float* g_n1   = (const float*)d_in[24]; const float* b_n1   = (const float*)d_in[25];
    const float* W_ff   = (const float*)d_in[26]; const float* b_ff   = (const float*)d_in[27];
    const float* g_n3   = (const float*)d_in[28]; const float* b_n3   = (const float*)d_in[29];
    float* out = (float*)d_out;

    short* attn_out = (short*)d_ws;                       // [30000*256] bf16
    short* value    = attn_out + (size_t)ROWS * 256;      // [30000*256] bf16 head-major
    float* S_oa     = (float*)(value + (size_t)ROWS * 256); // [30000*96] f32
    short* WT_dsa   = (short*)(S_oa + (size_t)ROWS * 96);
    short* WT_val   = WT_dsa + 65536;
    short* WT_ff    = WT_val + 65536;
    short* WT_c     = WT_ff + 65536;
    short* WT_oa    = WT_c + 65536;                       // 96*256
    float* bc       = (float*)(WT_oa + 96 * 256);
    float* b_oa     = bc + 256;

    dim3 blk(256);
    const int GB = (ROWS + 63) / 64;   // 469

    prep_all<<<401, blk, 0, stream>>>(
        W_dsa, W_val, W_ff, W_out, W_csa, b_out, b_csa, W_off, W_attn, b_off, b_attn,
        WT_dsa, WT_val, WT_ff, WT_c, bc, WT_oa, b_oa);

    // S_oa = (tgt+qpos)@[W_off|W_attn]+b  (independent of value path)
    oa_gemm<<<GB, blk, 0, stream>>>(tgt, query_pos, WT_oa, b_oa, S_oa, ROWS);

    // value = mask(LN(src@W_dsa+b_dsa) @ W_val + b_val), head-major
    fused2<0><<<GB, blk, 0, stream>>>(
        src, WT_dsa, b_dsa, nullptr, g_nds, b_nds,
        WT_val, b_val, value, mask, nullptr, nullptr, ROWS);

    // attn_out = deform-sample (softmax fused), high-TLP grid
    deform_sample<<<ROWS * 8 / 32, blk, 0, stream>>>(value, S_oa, refp, attn_out);

    // out = LN3(t + gelu(t@W_ff+b_ff)), t = LN1(tgt + attn_out@Wc+bc)
    fused2<1><<<GB, blk, 0, stream>>>(
        attn_out, WT_c, bc, tgt, g_n1, b_n1,
        WT_ff, b_ff, out, nullptr, g_n3, b_n3, ROWS);
}